// Round 10
// baseline (182.037 us; speedup 1.0000x reference)
//
#include <hip/hip_runtime.h>
#include <hip/hip_fp16.h>

#define N_PTS 100000
#define MU_F  100.0f
#define BUCKET 8192

typedef unsigned int uint;
typedef _Float16 h2 __attribute__((ext_vector_type(2)));
typedef float f2 __attribute__((ext_vector_type(2)));

#define E_SCALE 16384.0f
#define E_SCALE_INV (1.0f / 16384.0f)

static __device__ inline h2 h2pack(float a, float b) {
    return __builtin_bit_cast(h2, __builtin_amdgcn_cvt_pkrtz(a, b));
}
static __device__ inline float fdot2f(h2 a, h2 b, float c) {
    return __builtin_amdgcn_fdot2(a, b, c, false);
}
static __device__ inline h2 h2fma(h2 a, h2 b, h2 c) {
#if __has_builtin(__builtin_elementwise_fma)
    return __builtin_elementwise_fma(a, b, c);
#else
    return a * b + c;
#endif
}
static __device__ inline h2 h2max(h2 a, h2 b) {
#if __has_builtin(__builtin_elementwise_max)
    return __builtin_elementwise_max(a, b);
#else
    h2 r;
    r.x = a.x > b.x ? a.x : b.x;
    r.y = a.y > b.y ? a.y : b.y;
    return r;
#endif
}

// ---------------------------------------------------------------------------
// K1 fused prep: [0,800) encode (32 rows x 25 chunks) | [800,2363) transpose
// | [2363,2559) bucketed counting-sort scatter (bucket c starts at c*BUCKET)
// ---------------------------------------------------------------------------
#define ENC_BLKS 800             // 32 rows x 25 chunks of 4000
#define TR_BLKS  1563            // ceil(100000/64)
#define SC_BLKS  196             // 196*512 >= 100000

__global__ __launch_bounds__(256) void k_prep(const float* __restrict__ x,
                                              const float* __restrict__ encW,
                                              const float* __restrict__ encB,
                                              const float* __restrict__ dec,
                                              const int* __restrict__ labels,
                                              float* __restrict__ enc,
                                              __half* __restrict__ decT,
                                              int* __restrict__ gcur,
                                              int* __restrict__ perm) {
    int b = blockIdx.x;
    if (b < ENC_BLKS) {
        // ----- encode: enc[row] = x . encW[row,:] + encB[row]
        int row = b & 31;
        int chunk = b >> 5;              // 0..24
        const int CH = 4000;
        int base = chunk * CH;
        const float4* W4 = reinterpret_cast<const float4*>(encW + (size_t)row * N_PTS + base);
        const float4* x4 = reinterpret_cast<const float4*>(x + base);
        const int nv = CH / 4;           // 1000
        float acc = 0.f;
        for (int idx = threadIdx.x; idx < nv; idx += 256) {
            float4 w = W4[idx];
            float4 xv = x4[idx];
            acc += w.x * xv.x + w.y * xv.y + w.z * xv.z + w.w * xv.w;
        }
        #pragma unroll
        for (int off = 32; off > 0; off >>= 1) acc += __shfl_down(acc, off);
        __shared__ float sred[4];
        int wid = threadIdx.x >> 6;
        if ((threadIdx.x & 63) == 0) sred[wid] = acc;
        __syncthreads();
        if (threadIdx.x == 0) {
            float s = sred[0] + sred[1] + sred[2] + sred[3];
            if (chunk == 0) s += encB[row];
            atomicAdd(enc + row, s);
        }
    } else if (b < ENC_BLKS + TR_BLKS) {
        // ----- transpose dec [32,N] f32 -> decT [N,32] fp16 (64B rows)
        __shared__ float tile[32][65];
        int j0 = (b - ENC_BLKS) * 64;
        int col = threadIdx.x & 63;
        int r0 = threadIdx.x >> 6;       // 0..3
        #pragma unroll
        for (int it = 0; it < 8; ++it) {
            int row = it * 4 + r0;
            int j = j0 + col;
            float v = (j < N_PTS) ? dec[(size_t)row * N_PTS + j] : 0.f;
            tile[row][col] = v;
        }
        __syncthreads();
        #pragma unroll
        for (int it = 0; it < 4; ++it) {
            int idx = it * 256 + threadIdx.x;
            int j = idx >> 4;            // 0..63
            int p = idx & 15;            // i-pair
            int jj = j0 + j;
            if (jj < N_PTS) {
                __half2 h = __halves2half2(__float2half(tile[2 * p][j]),
                                           __float2half(tile[2 * p + 1][j]));
                *reinterpret_cast<__half2*>(decT + (size_t)jj * 32 + 2 * p) = h;
            }
        }
    } else {
        // ----- bucketed scatter: perm[c*BUCKET + pos] = j
        __shared__ int lh[16], lbase[16], lcur[16];
        const int CHUNK = 512;
        int start = (b - ENC_BLKS - TR_BLKS) * CHUNK;
        int end = min(start + CHUNK, N_PTS);
        if (threadIdx.x < 16) { lh[threadIdx.x] = 0; lcur[threadIdx.x] = 0; }
        __syncthreads();
        for (int j = start + threadIdx.x; j < end; j += 256)
            atomicAdd(&lh[labels[j]], 1);
        __syncthreads();
        if (threadIdx.x < 16)
            lbase[threadIdx.x] = threadIdx.x * BUCKET +
                                 atomicAdd(&gcur[threadIdx.x], lh[threadIdx.x]);
        __syncthreads();
        for (int j = start + threadIdx.x; j < end; j += 256) {
            int c = labels[j];
            int lpos = atomicAdd(&lcur[c], 1);
            perm[lbase[c] + lpos] = j;
        }
    }
}

// ---------------------------------------------------------------------------
// helper: thread i<32 computes invL[i] = 1/(sigmoid(enc.bw_w[i*16+c])*MU/60)^2
// ---------------------------------------------------------------------------
__device__ inline void build_invC(const float* __restrict__ encL,
                                  const float* __restrict__ bw_w,
                                  const float* __restrict__ bw_b,
                                  float* __restrict__ invCL, int c) {
    if (threadIdx.x < 32) {
        int r = threadIdx.x * 16 + c;
        float z = bw_b[r];
        const float* wr = bw_w + r * 32;
        #pragma unroll
        for (int p = 0; p < 32; ++p) z = fmaf(encL[p], wr[p], z);
        float s = 1.f / (1.f + __expf(-z));
        float wmu = s * (MU_F / 60.0f);
        invCL[threadIdx.x] = 1.f / (wmu * wmu);
    }
}

// ---------------------------------------------------------------------------
// K2: S partials, float2-packed inner (v_pk_fma_f32), 2-deep prefetch.
// block = (c, ch): 16 x 64 = 1024 blocks x 256 thr. Direct global atomics
// into pre-zeroed S (1024 adds/block onto 1024 addrs — spread over kernel
// lifetime, ~µs-level cost; saves the S_part traffic + reduce dispatch).
// ---------------------------------------------------------------------------
__global__ __launch_bounds__(256, 4) void k_S_sorted(const float* __restrict__ enc_g,
                                                     const float* __restrict__ bw_w,
                                                     const float* __restrict__ bw_b,
                                                     const float* __restrict__ nd,
                                                     const int* __restrict__ perm,
                                                     const int* __restrict__ gcur,
                                                     float* __restrict__ S) {
    __shared__ float encL[32], invCL[32];
    __shared__ float Sloc[1024];
    int b = blockIdx.x;
    int c = b & 15;
    int ch = b >> 4;                     // 0..63
    if (threadIdx.x < 32) encL[threadIdx.x] = enc_g[threadIdx.x];
    for (int t = threadIdx.x; t < 1024; t += 256) Sloc[t] = 0.f;
    __syncthreads();
    build_invC(encL, bw_w, bw_b, invCL, c);
    __syncthreads();

    f2 inv2[16];
    #pragma unroll
    for (int t = 0; t < 16; ++t) { inv2[t].x = invCL[2 * t]; inv2[t].y = invCL[2 * t + 1]; }

    int bs = c * BUCKET;
    int cnt = gcur[c];
    int lane = threadIdx.x & 63;
    int kk = lane & 31;
    int jh = lane >> 5;
    int gw = ch * 4 + (threadIdx.x >> 6);   // wave within c: 0..255
    const int nw = 64 * 4;                  // 256
    int npairs = (cnt + 1) >> 1;

    f2 acc2[16];
    #pragma unroll
    for (int t = 0; t < 16; ++t) { acc2[t].x = 0.f; acc2[t].y = 0.f; }

    if (gw < npairs) {
        auto ld = [&](int pc, float& d, bool& v) {
            bool ok = pc < npairs;
            v = ok && (2 * pc + jh) < cnt;
            int p = v ? (bs + 2 * pc + jh) : bs;
            int j = __builtin_nontemporal_load(&perm[p]);
            d = __builtin_nontemporal_load(&nd[(size_t)j * 32 + kk]);
        };
        int pp = gw;
        float dA, dB; bool vA, vB;
        ld(pp, dA, vA);
        ld(pp + nw, dB, vB);
        while (pp < npairs) {
            float dC; bool vC;
            ld(pp + 2 * nw, dC, vC);
            float d2 = vA ? dA * dA : 1e30f;
            f2 md2; md2.x = -d2; md2.y = -d2;
            f2 onev; onev.x = 1.f; onev.y = 1.f;
            #pragma unroll
            for (int t = 0; t < 16; ++t) {
                f2 w = md2 * inv2[t] + onev;     // v_pk_fma_f32
                w.x = fmaxf(w.x, 0.f);
                w.y = fmaxf(w.y, 0.f);
                acc2[t] += w;                    // v_pk_add_f32
            }
            dA = dB; vA = vB; dB = dC; vB = vC;
            pp += nw;
        }
    }
    #pragma unroll
    for (int t = 0; t < 16; ++t) {
        acc2[t].x += __shfl_xor(acc2[t].x, 32);
        acc2[t].y += __shfl_xor(acc2[t].y, 32);
    }
    if (jh == 0) {
        #pragma unroll
        for (int t = 0; t < 16; ++t) {
            atomicAdd(&Sloc[(2 * t) * 32 + kk], acc2[t].x);
            atomicAdd(&Sloc[(2 * t + 1) * 32 + kk], acc2[t].y);
        }
    }
    __syncthreads();
    for (int t = threadIdx.x; t < 1024; t += 256) {
        float v = Sloc[t];
        if (v != 0.f) atomicAdd(&S[t], v);
    }
}

// ---------------------------------------------------------------------------
// K3 (main): quad-broadcast structure + packed-fp16 inner.
// Lane L: R=L>>2 (row sub-index 0..15), q=L&3 (16B quad of 64B decT row).
// Stage s: (jsel, kk) = (s>>1, (s&1)*16 + R). Quad lanes broadcast-load the
// same nid/nd scalar; gathers touch 16 lines/instr. Per 2 i:
// v_pk_fma_f16 + v_pk_max_f16 + v_pk_mul_f16 + v_dot2_f32_f16.
// Pipeline: j-pair 2 ahead, ids/d 1 ahead. 8 waves/SIMD for latency hiding.
// ---------------------------------------------------------------------------
__global__ __launch_bounds__(256, 8) void k_main(const float* __restrict__ enc_g,
                                                 const float* __restrict__ bw_w,
                                                 const float* __restrict__ bw_b,
                                                 const float* __restrict__ S_g,
                                                 const float* __restrict__ nd,
                                                 const int* __restrict__ nid,
                                                 const int* __restrict__ perm,
                                                 const int* __restrict__ gcur,
                                                 const __half* __restrict__ decT,
                                                 float* __restrict__ out) {
    __shared__ float encL[32], invCL[32];
    __shared__ float ELf[1024];          // E[i][kk] * E_SCALE
    int c = blockIdx.x & 15;
    int ch = blockIdx.x >> 4;            // 0..127
    if (threadIdx.x < 32) encL[threadIdx.x] = enc_g[threadIdx.x];
    __syncthreads();
    build_invC(encL, bw_w, bw_b, invCL, c);
    for (int t = threadIdx.x; t < 1024; t += 256)
        ELf[t] = encL[t >> 5] / S_g[t] * E_SCALE;
    __syncthreads();

    int lane = threadIdx.x & 63;
    int R = lane >> 2;                   // 0..15
    int q = lane & 3;                    // i-quarter / row quad

    h2 invh[4], EhA[4], EhB[4];
    #pragma unroll
    for (int t = 0; t < 4; ++t) {
        int i0 = q * 8 + 2 * t;
        invh[t] = h2pack(fminf(invCL[i0], 6.0e4f), fminf(invCL[i0 + 1], 6.0e4f));
        EhA[t] = h2pack(ELf[i0 * 32 + R], ELf[(i0 + 1) * 32 + R]);
        EhB[t] = h2pack(ELf[i0 * 32 + R + 16], ELf[(i0 + 1) * 32 + R + 16]);
    }
    const h2 zero2 = h2pack(0.f, 0.f);
    const h2 one2 = h2pack(1.f, 1.f);

    int bs = c * BUCKET;
    int cnt = gcur[c];
    int wv = ch * 4 + (threadIdx.x >> 6);   // wave within c: 0..511
    const int nw = 128 * 4;                 // 512
    int npairs = (cnt + 1) >> 1;
    const uint4* decQ = reinterpret_cast<const uint4*>(decT);
    if (wv >= npairs) return;

    auto load_pair = [&](int pp, int& j0, int& j1, bool& v1) {
        bool ok = pp < npairs;
        int p0 = ok ? (bs + 2 * pp) : bs;
        v1 = ok && ((2 * pp + 1) < cnt);
        j0 = perm[p0];
        j1 = perm[v1 ? p0 + 1 : p0];
    };
    auto load_ids = [&](int j0, int j1, int* id, float* dd) {
        #pragma unroll
        for (int s = 0; s < 4; ++s) {
            int jj = (s >> 1) ? j1 : j0;
            size_t idx = (size_t)jj * 32 + (s & 1) * 16 + R;
            id[s] = __builtin_nontemporal_load(&nid[idx]);
            dd[s] = __builtin_nontemporal_load(&nd[idx]);
        }
    };

    int pp = wv;
    int j0a, j1a, j0b, j1b; bool v1a, v1b;
    int ida[4]; float dda[4];
    load_pair(pp, j0a, j1a, v1a);
    load_ids(j0a, j1a, ida, dda);
    load_pair(pp + nw, j0b, j1b, v1b);

    while (pp < npairs) {
        uint4 r0 = decQ[(size_t)ida[0] * 4 + q];
        uint4 r1 = decQ[(size_t)ida[1] * 4 + q];
        uint4 r2 = decQ[(size_t)ida[2] * 4 + q];
        uint4 r3 = decQ[(size_t)ida[3] * 4 + q];
        int idb[4]; float ddb[4];
        load_ids(j0b, j1b, idb, ddb);
        int j0c, j1c; bool v1c;
        load_pair(pp + 2 * nw, j0c, j1c, v1c);

        float d20 = dda[0] * dda[0];
        float d21 = dda[1] * dda[1];
        float d22 = dda[2] * dda[2];
        float d23 = dda[3] * dda[3];
        h2 md0 = h2pack(-d20, -d20);
        h2 md1 = h2pack(-d21, -d21);
        h2 md2 = h2pack(-d22, -d22);
        h2 md3 = h2pack(-d23, -d23);

        float a0 = 0.f, a1 = 0.f, a2 = 0.f, a3 = 0.f;
        #pragma unroll
        for (int t = 0; t < 4; ++t) {
            uint dw0 = (t == 0) ? r0.x : (t == 1) ? r0.y : (t == 2) ? r0.z : r0.w;
            uint dw1 = (t == 0) ? r1.x : (t == 1) ? r1.y : (t == 2) ? r1.z : r1.w;
            uint dw2 = (t == 0) ? r2.x : (t == 1) ? r2.y : (t == 2) ? r2.z : r2.w;
            uint dw3 = (t == 0) ? r3.x : (t == 1) ? r3.y : (t == 2) ? r3.z : r3.w;
            {
                h2 w = h2max(h2fma(md0, invh[t], one2), zero2);
                a0 = fdot2f(w * EhA[t], __builtin_bit_cast(h2, dw0), a0);
            }
            {
                h2 w = h2max(h2fma(md1, invh[t], one2), zero2);
                a1 = fdot2f(w * EhB[t], __builtin_bit_cast(h2, dw1), a1);
            }
            {
                h2 w = h2max(h2fma(md2, invh[t], one2), zero2);
                a2 = fdot2f(w * EhA[t], __builtin_bit_cast(h2, dw2), a2);
            }
            {
                h2 w = h2max(h2fma(md3, invh[t], one2), zero2);
                a3 = fdot2f(w * EhB[t], __builtin_bit_cast(h2, dw3), a3);
            }
        }
        float u = a0 + a1;               // j0 partial
        float v = a2 + a3;               // j1 partial
        #pragma unroll
        for (int off = 32; off > 0; off >>= 1) {
            u += __shfl_xor(u, off);
            v += __shfl_xor(v, off);
        }
        if (lane == 0) __builtin_nontemporal_store(u * E_SCALE_INV, &out[j0a]);
        if (lane == 32 && v1a) __builtin_nontemporal_store(v * E_SCALE_INV, &out[j1a]);

        j0a = j0b; j1a = j1b; v1a = v1b;
        j0b = j0c; j1b = j1c; v1b = v1c;
        #pragma unroll
        for (int s = 0; s < 4; ++s) { ida[s] = idb[s]; dda[s] = ddb[s]; }
        pp += nw;
    }
}

// ---------------------------------------------------------------------------
extern "C" void kernel_launch(void* const* d_in, const int* in_sizes, int n_in,
                              void* d_out, int out_size, void* d_ws, size_t ws_size,
                              hipStream_t stream) {
    const float* x     = (const float*)d_in[0];
    const float* enc_w = (const float*)d_in[1];
    const float* enc_b = (const float*)d_in[2];
    const float* dec   = (const float*)d_in[3];
    const float* bw_w  = (const float*)d_in[4];
    const float* bw_b  = (const float*)d_in[5];
    const float* nd    = (const float*)d_in[6];
    const int*   nid   = (const int*)d_in[7];
    const int*   labels= (const int*)d_in[8];
    float* out = (float*)d_out;

    // ws layout:
    //   [0,128)              enc (32 f)
    //   [128,4224)           S (1024 f)
    //   [4224,4288)          gcur (16 i)
    //   [8192,532480)        perm (16 buckets x 8192 i, 512 KB)
    //   [532480,6932480)     decT (N*32 fp16, 6.4 MB)
    char* ws = (char*)d_ws;
    float* enc    = (float*)(ws + 0);
    float* S      = (float*)(ws + 128);
    int* gcur     = (int*)(ws + 4224);
    int* perm     = (int*)(ws + 8192);
    __half* decT  = (__half*)(ws + 532480);

    (void)hipMemsetAsync(d_ws, 0, 4288, stream);    // enc, S, gcur
    k_prep<<<dim3(ENC_BLKS + TR_BLKS + SC_BLKS), dim3(256), 0, stream>>>(
        x, enc_w, enc_b, dec, labels, enc, decT, gcur, perm);
    k_S_sorted<<<dim3(1024), dim3(256), 0, stream>>>(enc, bw_w, bw_b, nd, perm,
                                                     gcur, S);
    k_main<<<dim3(2048), dim3(256), 0, stream>>>(enc, bw_w, bw_b, S, nd, nid,
                                                 perm, gcur, decT, out);
}